// Round 10
// baseline (175.040 us; speedup 1.0000x reference)
//
#include <hip/hip_runtime.h>
#include <hip/hip_bf16.h>

#define MDIM 49
#define INF 128
#define OUTF 128
#define BDIM 16384
#define BT 64
#define TILES_PER_BLOCK 4
#define BLOCKS_PER_M (BDIM / (BT * TILES_PER_BLOCK))   // 64

typedef __attribute__((ext_vector_type(8))) short bf16x8;
typedef __attribute__((ext_vector_type(4))) float f32x4;

static __device__ __forceinline__ short f2bf(float f) {
  __hip_bfloat16 h = __float2bfloat16(f);
  union { __hip_bfloat16 h; unsigned short u; } c;
  c.h = h;
  return (short)c.u;
}

static __device__ __forceinline__ bf16x8 cvt8(f32x4 a, f32x4 b) {
  bf16x8 r;
  r[0] = f2bf(a[0]); r[1] = f2bf(a[1]); r[2] = f2bf(a[2]); r[3] = f2bf(a[3]);
  r[4] = f2bf(b[0]); r[5] = f2bf(b[1]); r[6] = f2bf(b[2]); r[7] = f2bf(b[3]);
  return r;
}

// LDS barrier that does NOT drain vmcnt: ds-op ordering only (lgkmcnt).
// Private global prefetch loads legally stay in flight across it.
static __device__ __forceinline__ void lds_barrier() {
  asm volatile("s_waitcnt lgkmcnt(0)\n\ts_barrier" ::: "memory");
}

__global__ __launch_bounds__(256) void so3_linear_kernel(
    const float* __restrict__ in, const float* __restrict__ wt,
    const float* __restrict__ bias, float* __restrict__ out) {
  const int m    = blockIdx.x;   // 0..48
  const int blk  = blockIdx.y;   // 0..BLOCKS_PER_M-1
  const int tid  = threadIdx.x;
  const int lane = tid & 63;
  const int wv   = tid >> 6;     // wave 0..3

  // expand_index: l = floor(sqrt(m))
  int l = 0;
  while ((l + 1) * (l + 1) <= m) ++l;

  // input tile staged as bf16, padded to 136 shorts/row (272 B stride: 2-way alias = free)
  __shared__ short lds[BT][INF + 8];

  // ---- weight fragments (operand B): wave wv owns output cols [wv*32, wv*32+32)
  const int colbase = wv * 32;
  const int col0    = colbase + (lane & 15);
  const int krow    = (lane >> 4) * 8;
  const float* wl   = wt + (size_t)l * OUTF * INF;
  bf16x8 bfrag[2][4];  // [col-tile][k-step]
#pragma unroll
  for (int ct = 0; ct < 2; ++ct) {
    const float* wp = wl + (size_t)(col0 + ct * 16) * INF + krow;
#pragma unroll
    for (int ks = 0; ks < 4; ++ks) {
      f32x4 w0 = *(const f32x4*)(wp + ks * 32);
      f32x4 w1 = *(const f32x4*)(wp + ks * 32 + 4);
      bfrag[ct][ks] = cvt8(w0, w1);
    }
  }
  float biasv[2];
  biasv[0] = bias[col0];
  biasv[1] = bias[col0 + 16];

  // staging map: thread -> (row r0 + 16p, 8-float chunk c8)
  const int c8 = (tid & 15) * 8;
  const int r0 = tid >> 4;
  const int b0 = blk * (TILES_PER_BLOCK * BT);

  const size_t rowstride = (size_t)MDIM * INF;  // 6272 floats between consecutive b

  // prefetch tile 0 into registers
  f32x4 pf[8];
  {
    const float* ip = in + ((size_t)(b0 + r0) * MDIM + m) * INF + c8;
#pragma unroll
    for (int p = 0; p < 4; ++p) {
      pf[2 * p]     = *(const f32x4*)(ip + p * 16 * rowstride);
      pf[2 * p + 1] = *(const f32x4*)(ip + p * 16 * rowstride + 4);
    }
  }

  for (int tt = 0; tt < TILES_PER_BLOCK; ++tt) {
    // convert current tile regs -> bf16 LDS
#pragma unroll
    for (int p = 0; p < 4; ++p) {
      *(bf16x8*)&lds[r0 + 16 * p][c8] = cvt8(pf[2 * p], pf[2 * p + 1]);
    }

    // issue next tile's global loads; they stay in flight across the
    // lgkm-only barriers and land under MFMA + stores.
    if (tt + 1 < TILES_PER_BLOCK) {
      const float* ip =
          in + ((size_t)(b0 + (tt + 1) * BT + r0) * MDIM + m) * INF + c8;
#pragma unroll
      for (int p = 0; p < 4; ++p) {
        pf[2 * p]     = *(const f32x4*)(ip + p * 16 * rowstride);
        pf[2 * p + 1] = *(const f32x4*)(ip + p * 16 * rowstride + 4);
      }
    }

    lds_barrier();  // ds_writes visible; prefetch NOT drained

    // compute: wave covers all 64 rows x its 32 cols, K=128
    f32x4 acc[4][2];
#pragma unroll
    for (int rt = 0; rt < 4; ++rt)
#pragma unroll
      for (int ct = 0; ct < 2; ++ct)
        acc[rt][ct] = (f32x4){0.f, 0.f, 0.f, 0.f};

#pragma unroll
    for (int rt = 0; rt < 4; ++rt) {
      const int arow = rt * 16 + (lane & 15);
#pragma unroll
      for (int ks = 0; ks < 4; ++ks) {
        bf16x8 a = *(const bf16x8*)&lds[arow][ks * 32 + krow];
        acc[rt][0] = __builtin_amdgcn_mfma_f32_16x16x32_bf16(
            a, bfrag[0][ks], acc[rt][0], 0, 0, 0);
        acc[rt][1] = __builtin_amdgcn_mfma_f32_16x16x32_bf16(
            a, bfrag[1][ks], acc[rt][1], 0, 0, 0);
      }
    }

    // epilogue: C/D layout col=lane&15, row=(lane>>4)*4+j.
    // SINGLE CHANGE vs r5: non-temporal stores — output is write-once,
    // never re-read; stop churning L3 (keep input resident across replays).
    const int btile = b0 + tt * BT;
#pragma unroll
    for (int rt = 0; rt < 4; ++rt) {
      const int rbase = btile + rt * 16 + (lane >> 4) * 4;
#pragma unroll
      for (int ct = 0; ct < 2; ++ct) {
        const int col = colbase + ct * 16 + (lane & 15);
        const float badd = (m == 0) ? biasv[ct] : 0.0f;
#pragma unroll
        for (int j = 0; j < 4; ++j) {
          __builtin_nontemporal_store(
              acc[rt][ct][j] + badd,
              &out[((size_t)(rbase + j) * MDIM + m) * OUTF + col]);
        }
      }
    }

    lds_barrier();  // ds_reads done before next tile's ds_writes
  }
}

extern "C" void kernel_launch(void* const* d_in, const int* in_sizes, int n_in,
                              void* d_out, int out_size, void* d_ws, size_t ws_size,
                              hipStream_t stream) {
  const float* in   = (const float*)d_in[0];
  const float* wt   = (const float*)d_in[1];
  const float* bias = (const float*)d_in[2];
  float* out        = (float*)d_out;
  dim3 grid(MDIM, BLOCKS_PER_M);
  so3_linear_kernel<<<grid, dim3(256), 0, stream>>>(in, wt, bias, out);
}

// Round 11
// 164.489 us; speedup vs baseline: 1.0641x; 1.0641x over previous
//
#include <hip/hip_runtime.h>
#include <hip/hip_bf16.h>

#define MDIM 49
#define INF 128
#define OUTF 128
#define BDIM 16384
#define BT 64
#define TILES_PER_BLOCK 4
#define BLOCKS_PER_M (BDIM / (BT * TILES_PER_BLOCK))   // 64
#define EPLD 132   // epilogue LDS row pitch (f32), padded

typedef __attribute__((ext_vector_type(8))) short bf16x8;
typedef __attribute__((ext_vector_type(4))) float f32x4;

static __device__ __forceinline__ short f2bf(float f) {
  __hip_bfloat16 h = __float2bfloat16(f);
  union { __hip_bfloat16 h; unsigned short u; } c;
  c.h = h;
  return (short)c.u;
}

static __device__ __forceinline__ bf16x8 cvt8(f32x4 a, f32x4 b) {
  bf16x8 r;
  r[0] = f2bf(a[0]); r[1] = f2bf(a[1]); r[2] = f2bf(a[2]); r[3] = f2bf(a[3]);
  r[4] = f2bf(b[0]); r[5] = f2bf(b[1]); r[6] = f2bf(b[2]); r[7] = f2bf(b[3]);
  return r;
}

// LDS barrier that does NOT drain vmcnt: ds-op ordering only (lgkmcnt).
// Private global loads/stores legally stay in flight across it.
static __device__ __forceinline__ void lds_barrier() {
  asm volatile("s_waitcnt lgkmcnt(0)\n\ts_barrier" ::: "memory");
}

__global__ __launch_bounds__(256) void so3_linear_kernel(
    const float* __restrict__ in, const float* __restrict__ wt,
    const float* __restrict__ bias, float* __restrict__ out) {
  const int m    = blockIdx.x;   // 0..48
  const int blk  = blockIdx.y;   // 0..BLOCKS_PER_M-1
  const int tid  = threadIdx.x;
  const int lane = tid & 63;
  const int wv   = tid >> 6;     // wave 0..3

  // expand_index: l = floor(sqrt(m))
  int l = 0;
  while ((l + 1) * (l + 1) <= m) ++l;

  // staging: single-buffered bf16 tile (dbuf measured worse); 272 B stride pad
  __shared__ short lds[BT][INF + 8];
  // epilogue transpose buffer: 32 rows x 132 f32 (16.9 KB)
  __shared__ float ebuf[32][EPLD];

  // ---- weight fragments (A operand): wave wv owns o-cols [wv*32,+32)
  const int colbase = wv * 32;
  const int r16     = lane & 15;
  const int krow    = (lane >> 4) * 8;
  const float* wl   = wt + (size_t)l * OUTF * INF;
  bf16x8 wfrag[2][4];  // [o-tile][k-step]
#pragma unroll
  for (int ct = 0; ct < 2; ++ct) {
    const float* wp = wl + (size_t)(colbase + ct * 16 + r16) * INF + krow;
#pragma unroll
    for (int ks = 0; ks < 4; ++ks) {
      f32x4 w0 = *(const f32x4*)(wp + ks * 32);
      f32x4 w1 = *(const f32x4*)(wp + ks * 32 + 4);
      wfrag[ct][ks] = cvt8(w0, w1);
    }
  }
  // bias per lane for D layout: lane holds o = colbase + ct*16 + (lane>>4)*4 + j
  f32x4 biasadd[2];
#pragma unroll
  for (int ct = 0; ct < 2; ++ct) {
    biasadd[ct] = (m == 0)
        ? *(const f32x4*)(bias + colbase + ct * 16 + (lane >> 4) * 4)
        : (f32x4){0.f, 0.f, 0.f, 0.f};
  }

  // staging map: thread -> (row r0 + 16p, 8-float chunk c8)
  const int c8 = (tid & 15) * 8;
  const int r0 = tid >> 4;
  const int b0 = blk * (TILES_PER_BLOCK * BT);

  const size_t rowstride = (size_t)MDIM * INF;  // 6272 floats between consecutive b

  // prologue: prefetch tile 0 into registers
  f32x4 pf[8];
  {
    const float* ip = in + ((size_t)(b0 + r0) * MDIM + m) * INF + c8;
#pragma unroll
    for (int p = 0; p < 4; ++p) {
      pf[2 * p]     = *(const f32x4*)(ip + p * 16 * rowstride);
      pf[2 * p + 1] = *(const f32x4*)(ip + p * 16 * rowstride + 4);
    }
  }

  for (int tt = 0; tt < TILES_PER_BLOCK; ++tt) {
    // convert current tile regs -> bf16 LDS
#pragma unroll
    for (int p = 0; p < 4; ++p) {
      *(bf16x8*)&lds[r0 + 16 * p][c8] = cvt8(pf[2 * p], pf[2 * p + 1]);
    }

    // issue next tile's loads; in flight across all lgkm-only barriers
    if (tt + 1 < TILES_PER_BLOCK) {
      const float* ip =
          in + ((size_t)(b0 + (tt + 1) * BT + r0) * MDIM + m) * INF + c8;
#pragma unroll
      for (int p = 0; p < 4; ++p) {
        pf[2 * p]     = *(const f32x4*)(ip + p * 16 * rowstride);
        pf[2 * p + 1] = *(const f32x4*)(ip + p * 16 * rowstride + 4);
      }
    }

    lds_barrier();  // B1: staging visible (also: prev tile's ebuf reads done)

    // compute: D[o][b] = W x X. acc[bt][ct]:
    // D col = lane&15 = b-within-16, D row = (lane>>4)*4+j = o-within-16.
    f32x4 acc[4][2];
#pragma unroll
    for (int bt = 0; bt < 4; ++bt)
#pragma unroll
      for (int ct = 0; ct < 2; ++ct)
        acc[bt][ct] = (f32x4){0.f, 0.f, 0.f, 0.f};

#pragma unroll
    for (int bt = 0; bt < 4; ++bt) {
      const int arow = bt * 16 + r16;
#pragma unroll
      for (int ks = 0; ks < 4; ++ks) {
        bf16x8 a = *(const bf16x8*)&lds[arow][ks * 32 + krow];
        acc[bt][0] = __builtin_amdgcn_mfma_f32_16x16x32_bf16(
            wfrag[0][ks], a, acc[bt][0], 0, 0, 0);
        acc[bt][1] = __builtin_amdgcn_mfma_f32_16x16x32_bf16(
            wfrag[1][ks], a, acc[bt][1], 0, 0, 0);
      }
    }

    // epilogue via LDS transpose, two 32-row halves -> 512 B-contiguous stores
    const int btile = b0 + tt * BT;
#pragma unroll
    for (int h = 0; h < 2; ++h) {
      // deposit: lane writes f32x4 along o for rows of this half
#pragma unroll
      for (int q = 0; q < 2; ++q) {        // bt = 2h + q
        const int bt = 2 * h + q;
        const int r  = q * 16 + r16;       // row within half (0..31)
#pragma unroll
        for (int ct = 0; ct < 2; ++ct) {
          f32x4 v = acc[bt][ct];
          v[0] += biasadd[ct][0]; v[1] += biasadd[ct][1];
          v[2] += biasadd[ct][2]; v[3] += biasadd[ct][3];
          *(f32x4*)&ebuf[r][colbase + ct * 16 + (lane >> 4) * 4] = v;
        }
      }
      lds_barrier();  // deposits visible

      // cooperative store: 32 lanes cover one full 512 B output row
#pragma unroll
      for (int k = 0; k < 4; ++k) {
        const int row32 = (tid >> 5) + k * 8;
        const int col4  = tid & 31;
        f32x4 v = *(const f32x4*)&ebuf[row32][col4 * 4];
        const int b = btile + h * 32 + row32;
        *(f32x4*)(out + ((size_t)b * MDIM + m) * OUTF + col4 * 4) = v;
      }
      if (h == 0) lds_barrier();  // half-0 reads done before half-1 deposits
      // (half-1 reads are protected by the next iteration's B1)
    }
  }
}

extern "C" void kernel_launch(void* const* d_in, const int* in_sizes, int n_in,
                              void* d_out, int out_size, void* d_ws, size_t ws_size,
                              hipStream_t stream) {
  const float* in   = (const float*)d_in[0];
  const float* wt   = (const float*)d_in[1];
  const float* bias = (const float*)d_in[2];
  float* out        = (float*)d_out;
  dim3 grid(MDIM, BLOCKS_PER_M);
  so3_linear_kernel<<<grid, dim3(256), 0, stream>>>(in, wt, bias, out);
}